// Round 2
// baseline (1236.703 us; speedup 1.0000x reference)
//
#include <hip/hip_runtime.h>
#include <hip/hip_bf16.h>
#include <math.h>

// Problem constants
#define BB 8
#define SS 1024
#define DD 2048
#define HH 16
#define DHD 128

typedef float  v4f  __attribute__((ext_vector_type(4)));
typedef short  v4s  __attribute__((ext_vector_type(4)));
typedef short  v8s  __attribute__((ext_vector_type(8)));
typedef __bf16 v8bf __attribute__((ext_vector_type(8)));

#define GLOBAL_AS __attribute__((address_space(1)))
#define LDS_AS    __attribute__((address_space(3)))

__device__ __forceinline__ unsigned short f2b(float f) {
    union { float f; unsigned int u; } x; x.f = f;
    unsigned int r = x.u + 0x7fffu + ((x.u >> 16) & 1u);  // RNE
    return (unsigned short)(r >> 16);
}

// ---------------------------------------------------------------------------
// fp32 -> bf16 elementwise convert (memory-bound)
// ---------------------------------------------------------------------------
__global__ __launch_bounds__(256) void cvt_f32_bf16(const float* __restrict__ src,
                                                    unsigned short* __restrict__ dst,
                                                    int n4) {
    int i = blockIdx.x * blockDim.x + threadIdx.x;
    int stride = gridDim.x * blockDim.x;
    for (; i < n4; i += stride) {
        v4f f = ((const v4f*)src)[i];
        v4s o;
        o[0] = (short)f2b(f[0]); o[1] = (short)f2b(f[1]);
        o[2] = (short)f2b(f[2]); o[3] = (short)f2b(f[3]);
        ((v4s*)dst)[i] = o;
    }
}

// ---------------------------------------------------------------------------
// W (K x N fp32, row-major) -> WT (N x K bf16, row-major). LDS-tiled transpose.
// ---------------------------------------------------------------------------
__global__ __launch_bounds__(256) void wtrans_kernel(const float* __restrict__ W,
                                                     unsigned short* __restrict__ WT) {
    __shared__ float t[64][65];
    int nb = blockIdx.x * 64;
    int kb = blockIdx.y * 64;
    int tr = threadIdx.x >> 4;         // 0..15
    int tc = (threadIdx.x & 15) * 4;   // 0..60
#pragma unroll
    for (int i = 0; i < 4; i++) {
        int k = kb + tr + i * 16;
        v4f v = *(const v4f*)(W + (size_t)k * DD + nb + tc);
        t[tr + i * 16][tc + 0] = v[0];
        t[tr + i * 16][tc + 1] = v[1];
        t[tr + i * 16][tc + 2] = v[2];
        t[tr + i * 16][tc + 3] = v[3];
    }
    __syncthreads();
#pragma unroll
    for (int i = 0; i < 4; i++) {
        int n = nb + tr + i * 16;
        v4s o;
#pragma unroll
        for (int j = 0; j < 4; j++) o[j] = (short)f2b(t[tc + j][tr + i * 16]);
        *(v4s*)(WT + (size_t)n * DD + kb + tc) = o;
    }
}

// ---------------------------------------------------------------------------
// m97-style bf16 GEMM: C[m][n] = sum_k A[m][k] * BT[n][k]
// ---------------------------------------------------------------------------
__global__ __launch_bounds__(256) void gemm_bt(const unsigned short* __restrict__ A,
                                               const unsigned short* __restrict__ BT,
                                               unsigned short* __restrict__ C,
                                               float scale, int vmode,
                                               int M, int N, int K) {
    __shared__ unsigned short sA[128 * 32];
    __shared__ unsigned short sB[128 * 32];
    int tid  = threadIdx.x;
    int lane = tid & 63, w = tid >> 6;
    int bm = blockIdx.y * 128, bn = blockIdx.x * 128;
    int wm = (w & 1) * 64, wn = (w >> 1) * 64;
    int qcol = lane & 15, quad = lane >> 4;

    int srow = lane >> 2;           // 0..15
    int scol = (lane & 3) * 8;      // ushort offset (8 ushort = 16B)
    const unsigned short* gA0 = A  + (size_t)(bm + w * 32 + srow) * K + scol;
    const unsigned short* gA1 = gA0 + (size_t)16 * K;
    const unsigned short* gB0 = BT + (size_t)(bn + w * 32 + srow) * K + scol;
    const unsigned short* gB1 = gB0 + (size_t)16 * K;
    unsigned short* lA0 = &sA[(w * 32) * 32];
    unsigned short* lA1 = &sA[(w * 32 + 16) * 32];
    unsigned short* lB0 = &sB[(w * 32) * 32];
    unsigned short* lB1 = &sB[(w * 32 + 16) * 32];

    v4f acc[4][4];
#pragma unroll
    for (int i = 0; i < 4; i++)
#pragma unroll
        for (int j = 0; j < 4; j++) acc[i][j] = (v4f){0.f, 0.f, 0.f, 0.f};

    for (int kt = 0; kt < K; kt += 32) {
        __syncthreads();
        __builtin_amdgcn_global_load_lds((const GLOBAL_AS void*)(gA0 + kt), (LDS_AS void*)lA0, 16, 0, 0);
        __builtin_amdgcn_global_load_lds((const GLOBAL_AS void*)(gA1 + kt), (LDS_AS void*)lA1, 16, 0, 0);
        __builtin_amdgcn_global_load_lds((const GLOBAL_AS void*)(gB0 + kt), (LDS_AS void*)lB0, 16, 0, 0);
        __builtin_amdgcn_global_load_lds((const GLOBAL_AS void*)(gB1 + kt), (LDS_AS void*)lB1, 16, 0, 0);
        __syncthreads();

        v8bf a[4], b[4];
#pragma unroll
        for (int tm = 0; tm < 4; tm++)
            a[tm] = __builtin_bit_cast(v8bf, *(const v8s*)&sA[(wm + tm * 16 + qcol) * 32 + quad * 8]);
#pragma unroll
        for (int tn = 0; tn < 4; tn++)
            b[tn] = __builtin_bit_cast(v8bf, *(const v8s*)&sB[(wn + tn * 16 + qcol) * 32 + quad * 8]);
#pragma unroll
        for (int tm = 0; tm < 4; tm++)
#pragma unroll
            for (int tn = 0; tn < 4; tn++)
                acc[tm][tn] = __builtin_amdgcn_mfma_f32_16x16x32_bf16(a[tm], b[tn], acc[tm][tn], 0, 0, 0);
    }

    if (vmode == 0) {
#pragma unroll
        for (int tm = 0; tm < 4; tm++)
#pragma unroll
            for (int tn = 0; tn < 4; tn++)
#pragma unroll
                for (int r = 0; r < 4; r++) {
                    int row = bm + wm + tm * 16 + quad * 4 + r;
                    int col = bn + wn + tn * 16 + qcol;
                    C[(size_t)row * N + col] = f2b(acc[tm][tn][r] * scale);
                }
    } else {
#pragma unroll
        for (int tm = 0; tm < 4; tm++)
#pragma unroll
            for (int tn = 0; tn < 4; tn++)
#pragma unroll
                for (int r = 0; r < 4; r++) {
                    int row = bm + wm + tm * 16 + quad * 4 + r;
                    int col = bn + wn + tn * 16 + qcol;
                    size_t idx = ((size_t)(row >> 10) * 2048 + col) * 1024 + (row & 1023);
                    C[idx] = f2b(acc[tm][tn][r] * scale);
                }
    }
}

// ---------------------------------------------------------------------------
// Flash attention, S^T orientation, software-pipelined.
// K fragments: register double-buffer, prefetched one full 32-key tile ahead.
// V fragments: issued at the top of each tile's compute, consumed after
// S^T MFMAs + softmax (~350 cyc of cover). No LDS.
// ---------------------------------------------------------------------------
__global__ __launch_bounds__(256) void attn_kernel(const unsigned short* __restrict__ qh,
                                                   const unsigned short* __restrict__ kh,
                                                   const unsigned short* __restrict__ vt,
                                                   float* __restrict__ out) {
    int lane = threadIdx.x & 63, w = threadIdx.x >> 6;
    int b = blockIdx.z, h = blockIdx.y;
    int q0 = blockIdx.x * 64 + w * 16;
    int qcol = lane & 15, quad = lane >> 4;

    // Q fragments (B-operand of 16x16x32): n = q = lane&15, k = d
    const unsigned short* qp = qh + (size_t)(b * SS + q0 + qcol) * DD + h * DHD;
    v8bf bq[4];
#pragma unroll
    for (int kk = 0; kk < 4; kk++)
        bq[kk] = __builtin_bit_cast(v8bf, *(const v8s*)(qp + kk * 32 + quad * 8));

    const unsigned short* kp = kh + (size_t)b * SS * DD + h * DHD + (size_t)qcol * DD + quad * 8;
    const unsigned short* vp = vt + (size_t)(b * HH + h) * DHD * SS + (size_t)qcol * SS;

    float m_i = -1e30f, l_i = 0.f;
    v4f acc[8];
#pragma unroll
    for (int c = 0; c < 8; c++) acc[c] = (v4f){0.f, 0.f, 0.f, 0.f};

    auto loadK = [&](v8s* dst, int kb) {
        const unsigned short* k0 = kp + (size_t)kb * DD;
#pragma unroll
        for (int kk = 0; kk < 4; kk++) {
            dst[kk]     = *(const v8s*)(k0 + kk * 32);
            dst[4 + kk] = *(const v8s*)(k0 + (size_t)16 * DD + kk * 32);
        }
    };
    auto loadV = [&](v4s* dst, int kb) {
        const unsigned short* v0 = vp + kb + quad * 4;
#pragma unroll
        for (int c = 0; c < 8; c++) {
            dst[2 * c]     = *(const v4s*)(v0 + (size_t)c * 16 * SS);
            dst[2 * c + 1] = *(const v4s*)(v0 + (size_t)c * 16 * SS + 16);
        }
    };
    auto computeTile = [&](const v8s* kf, const v4s* vf) {
        v4f s0 = (v4f){0.f, 0.f, 0.f, 0.f};
        v4f s1 = (v4f){0.f, 0.f, 0.f, 0.f};
#pragma unroll
        for (int kk = 0; kk < 4; kk++)
            s0 = __builtin_amdgcn_mfma_f32_16x16x32_bf16(
                __builtin_bit_cast(v8bf, kf[kk]), bq[kk], s0, 0, 0, 0);
#pragma unroll
        for (int kk = 0; kk < 4; kk++)
            s1 = __builtin_amdgcn_mfma_f32_16x16x32_bf16(
                __builtin_bit_cast(v8bf, kf[4 + kk]), bq[kk], s1, 0, 0, 0);
        // online softmax (base-2; log2(e) folded into qh scale)
        float mx = fmaxf(fmaxf(fmaxf(s0[0], s0[1]), fmaxf(s0[2], s0[3])),
                         fmaxf(fmaxf(s1[0], s1[1]), fmaxf(s1[2], s1[3])));
        mx = fmaxf(mx, __shfl_xor(mx, 16));
        mx = fmaxf(mx, __shfl_xor(mx, 32));
        float m_new = fmaxf(m_i, mx);
        float p0[4], p1[4], rs = 0.f;
#pragma unroll
        for (int r = 0; r < 4; r++) {
            p0[r] = exp2f(s0[r] - m_new);
            p1[r] = exp2f(s1[r] - m_new);
            rs += p0[r] + p1[r];
        }
        rs += __shfl_xor(rs, 16);
        rs += __shfl_xor(rs, 32);
        float alpha = exp2f(m_i - m_new);
        l_i = l_i * alpha + rs;
        m_i = m_new;
#pragma unroll
        for (int c = 0; c < 8; c++) {
            acc[c][0] *= alpha; acc[c][1] *= alpha;
            acc[c][2] *= alpha; acc[c][3] *= alpha;
        }
        v4s bp0, bp1;
#pragma unroll
        for (int r = 0; r < 4; r++) {
            bp0[r] = (short)f2b(p0[r]);
            bp1[r] = (short)f2b(p1[r]);
        }
#pragma unroll
        for (int c = 0; c < 8; c++) {
            acc[c] = __builtin_amdgcn_mfma_f32_16x16x16bf16_1k(vf[2 * c],     bp0, acc[c], 0, 0, 0);
            acc[c] = __builtin_amdgcn_mfma_f32_16x16x16bf16_1k(vf[2 * c + 1], bp1, acc[c], 0, 0, 0);
        }
    };

    v8s kfA[8], kfB[8];
    v4s vf0[16], vf1[16];
    loadK(kfA, 0);
    for (int kb = 0; kb < SS; kb += 64) {
        // half 1: tile kb (in kfA); prefetch K for kb+32; issue V for kb early
        loadK(kfB, kb + 32);
        loadV(vf0, kb);
        computeTile(kfA, vf0);
        // half 2: tile kb+32 (in kfB); prefetch K for kb+64; issue V for kb+32
        int kbn = (kb + 64 < SS) ? kb + 64 : 0;
        loadK(kfA, kbn);
        loadV(vf1, kb + 32);
        computeTile(kfB, vf1);
    }

    float rl = 1.0f / l_i;
    float* op = out + (size_t)(b * SS + q0 + qcol) * DD + h * DHD;
#pragma unroll
    for (int c = 0; c < 8; c++)
#pragma unroll
        for (int r = 0; r < 4; r++)
            op[c * 16 + quad * 4 + r] = acc[c][r] * rl;
}

// ---------------------------------------------------------------------------
// Launch. ws layout (needs 136 MB):
//   abuf @ 0 MB (32) | wbuf @ 32 (8) | qh @ 40 (32) | kh @ 72 (32) | vt @ 104 (32)
// ---------------------------------------------------------------------------
extern "C" void kernel_launch(void* const* d_in, const int* in_sizes, int n_in,
                              void* d_out, int out_size, void* d_ws, size_t ws_size,
                              hipStream_t stream) {
    const float* ins[3]  = {(const float*)d_in[0], (const float*)d_in[1], (const float*)d_in[2]};
    const float* wins[3] = {(const float*)d_in[3], (const float*)d_in[4], (const float*)d_in[5]};
    char* ws = (char*)d_ws;
    unsigned short* abuf = (unsigned short*)(ws);
    unsigned short* wbuf = (unsigned short*)(ws + (size_t)32 * 1024 * 1024);
    unsigned short* qhb  = (unsigned short*)(ws + (size_t)40 * 1024 * 1024);
    unsigned short* khb  = (unsigned short*)(ws + (size_t)72 * 1024 * 1024);
    unsigned short* vtb  = (unsigned short*)(ws + (size_t)104 * 1024 * 1024);
    float* out = (float*)d_out;

    unsigned short* outs[3] = {qhb, khb, vtb};
    const float qscale = 0.12753139626246937f;  // log2(e)/sqrt(128)
    float scales[3] = {qscale, 1.f, 1.f};
    int   vmodes[3] = {0, 0, 1};

    for (int i = 0; i < 3; i++) {
        cvt_f32_bf16<<<dim3(4096), dim3(256), 0, stream>>>(ins[i], abuf, (BB * SS * DD) / 4);
        wtrans_kernel<<<dim3(32, 32), dim3(256), 0, stream>>>(wins[i], wbuf);
        gemm_bt<<<dim3(16, 64), dim3(256), 0, stream>>>(abuf, wbuf, outs[i],
                                                        scales[i], vmodes[i],
                                                        BB * SS, DD, DD);
    }
    attn_kernel<<<dim3(SS / 64, HH, BB), dim3(256), 0, stream>>>(qhb, khb, vtb, out);
}

// Round 3
// 691.096 us; speedup vs baseline: 1.7895x; 1.7895x over previous
//
#include <hip/hip_runtime.h>
#include <hip/hip_bf16.h>
#include <math.h>

// Problem constants
#define BB 8
#define SS 1024
#define DD 2048
#define HH 16
#define DHD 128

typedef float  v4f  __attribute__((ext_vector_type(4)));
typedef short  v4s  __attribute__((ext_vector_type(4)));
typedef short  v8s  __attribute__((ext_vector_type(8)));
typedef __bf16 v8bf __attribute__((ext_vector_type(8)));

#define GLOBAL_AS __attribute__((address_space(1)))
#define LDS_AS    __attribute__((address_space(3)))

__device__ __forceinline__ unsigned short f2b(float f) {
    union { float f; unsigned int u; } x; x.f = f;
    unsigned int r = x.u + 0x7fffu + ((x.u >> 16) & 1u);  // RNE
    return (unsigned short)(r >> 16);
}

// ---------------------------------------------------------------------------
// fp32 -> bf16 elementwise convert (memory-bound)
// ---------------------------------------------------------------------------
__global__ __launch_bounds__(256) void cvt_f32_bf16(const float* __restrict__ src,
                                                    unsigned short* __restrict__ dst,
                                                    int n4) {
    int i = blockIdx.x * blockDim.x + threadIdx.x;
    int stride = gridDim.x * blockDim.x;
    for (; i < n4; i += stride) {
        v4f f = ((const v4f*)src)[i];
        v4s o;
        o[0] = (short)f2b(f[0]); o[1] = (short)f2b(f[1]);
        o[2] = (short)f2b(f[2]); o[3] = (short)f2b(f[3]);
        ((v4s*)dst)[i] = o;
    }
}

// ---------------------------------------------------------------------------
// W (K x N fp32, row-major) -> WT (N x K bf16, row-major). LDS-tiled transpose.
// ---------------------------------------------------------------------------
__global__ __launch_bounds__(256) void wtrans_kernel(const float* __restrict__ W,
                                                     unsigned short* __restrict__ WT) {
    __shared__ float t[64][65];
    int nb = blockIdx.x * 64;
    int kb = blockIdx.y * 64;
    int tr = threadIdx.x >> 4;         // 0..15
    int tc = (threadIdx.x & 15) * 4;   // 0..60
#pragma unroll
    for (int i = 0; i < 4; i++) {
        int k = kb + tr + i * 16;
        v4f v = *(const v4f*)(W + (size_t)k * DD + nb + tc);
        t[tr + i * 16][tc + 0] = v[0];
        t[tr + i * 16][tc + 1] = v[1];
        t[tr + i * 16][tc + 2] = v[2];
        t[tr + i * 16][tc + 3] = v[3];
    }
    __syncthreads();
#pragma unroll
    for (int i = 0; i < 4; i++) {
        int n = nb + tr + i * 16;
        v4s o;
#pragma unroll
        for (int j = 0; j < 4; j++) o[j] = (short)f2b(t[tc + j][tr + i * 16]);
        *(v4s*)(WT + (size_t)n * DD + kb + tc) = o;
    }
}

// ---------------------------------------------------------------------------
// m97-style bf16 GEMM: C[m][n] = sum_k A[m][k] * BT[n][k]
// ---------------------------------------------------------------------------
__global__ __launch_bounds__(256) void gemm_bt(const unsigned short* __restrict__ A,
                                               const unsigned short* __restrict__ BT,
                                               unsigned short* __restrict__ C,
                                               float scale, int vmode,
                                               int M, int N, int K) {
    __shared__ unsigned short sA[128 * 32];
    __shared__ unsigned short sB[128 * 32];
    int tid  = threadIdx.x;
    int lane = tid & 63, w = tid >> 6;
    int bm = blockIdx.y * 128, bn = blockIdx.x * 128;
    int wm = (w & 1) * 64, wn = (w >> 1) * 64;
    int qcol = lane & 15, quad = lane >> 4;

    int srow = lane >> 2;           // 0..15
    int scol = (lane & 3) * 8;      // ushort offset (8 ushort = 16B)
    const unsigned short* gA0 = A  + (size_t)(bm + w * 32 + srow) * K + scol;
    const unsigned short* gA1 = gA0 + (size_t)16 * K;
    const unsigned short* gB0 = BT + (size_t)(bn + w * 32 + srow) * K + scol;
    const unsigned short* gB1 = gB0 + (size_t)16 * K;
    unsigned short* lA0 = &sA[(w * 32) * 32];
    unsigned short* lA1 = &sA[(w * 32 + 16) * 32];
    unsigned short* lB0 = &sB[(w * 32) * 32];
    unsigned short* lB1 = &sB[(w * 32 + 16) * 32];

    v4f acc[4][4];
#pragma unroll
    for (int i = 0; i < 4; i++)
#pragma unroll
        for (int j = 0; j < 4; j++) acc[i][j] = (v4f){0.f, 0.f, 0.f, 0.f};

    for (int kt = 0; kt < K; kt += 32) {
        __syncthreads();
        __builtin_amdgcn_global_load_lds((const GLOBAL_AS void*)(gA0 + kt), (LDS_AS void*)lA0, 16, 0, 0);
        __builtin_amdgcn_global_load_lds((const GLOBAL_AS void*)(gA1 + kt), (LDS_AS void*)lA1, 16, 0, 0);
        __builtin_amdgcn_global_load_lds((const GLOBAL_AS void*)(gB0 + kt), (LDS_AS void*)lB0, 16, 0, 0);
        __builtin_amdgcn_global_load_lds((const GLOBAL_AS void*)(gB1 + kt), (LDS_AS void*)lB1, 16, 0, 0);
        __syncthreads();

        v8bf a[4], b[4];
#pragma unroll
        for (int tm = 0; tm < 4; tm++)
            a[tm] = __builtin_bit_cast(v8bf, *(const v8s*)&sA[(wm + tm * 16 + qcol) * 32 + quad * 8]);
#pragma unroll
        for (int tn = 0; tn < 4; tn++)
            b[tn] = __builtin_bit_cast(v8bf, *(const v8s*)&sB[(wn + tn * 16 + qcol) * 32 + quad * 8]);
#pragma unroll
        for (int tm = 0; tm < 4; tm++)
#pragma unroll
            for (int tn = 0; tn < 4; tn++)
                acc[tm][tn] = __builtin_amdgcn_mfma_f32_16x16x32_bf16(a[tm], b[tn], acc[tm][tn], 0, 0, 0);
    }

    if (vmode == 0) {
#pragma unroll
        for (int tm = 0; tm < 4; tm++)
#pragma unroll
            for (int tn = 0; tn < 4; tn++)
#pragma unroll
                for (int r = 0; r < 4; r++) {
                    int row = bm + wm + tm * 16 + quad * 4 + r;
                    int col = bn + wn + tn * 16 + qcol;
                    C[(size_t)row * N + col] = f2b(acc[tm][tn][r] * scale);
                }
    } else {
#pragma unroll
        for (int tm = 0; tm < 4; tm++)
#pragma unroll
            for (int tn = 0; tn < 4; tn++)
#pragma unroll
                for (int r = 0; r < 4; r++) {
                    int row = bm + wm + tm * 16 + quad * 4 + r;
                    int col = bn + wn + tn * 16 + qcol;
                    size_t idx = ((size_t)(row >> 10) * 2048 + col) * 1024 + (row & 1023);
                    C[idx] = f2b(acc[tm][tn][r] * scale);
                }
    }
}

// ---------------------------------------------------------------------------
// Flash attention v3: LDS-staged K/V shared by all 4 waves, GEMM-style
// 2-barrier K-loop with global_load_lds width=16, 64-key tiles.
//
// Swizzle: LDS rows have power-of-2 byte strides (K: 256B, V: 128B), so
// naive fragment reads would be 16-way bank-conflicted. We XOR-permute the
// 16B chunks on the GLOBAL side of the staging load (per-lane global
// addresses are unconstrained; LDS dest must stay uniform + lane*16):
//   sK[key][chunk c] = K[key][c ^ (key&15)]   (16 chunks of 16B per row)
//   sV[d][chunk c]   = V^T[d][c ^ (d&7)]      (8 chunks of 16B per row)
// Readers XOR the same way -> 2-way-max aliasing (free per m136).
// ---------------------------------------------------------------------------
__global__ __launch_bounds__(256, 4) void attn_kernel(const unsigned short* __restrict__ qh,
                                                      const unsigned short* __restrict__ kh,
                                                      const unsigned short* __restrict__ vt,
                                                      float* __restrict__ out) {
    __shared__ __align__(16) unsigned short sK[64 * 128];   // [key][d] 64 rows x 256B
    __shared__ __align__(16) unsigned short sV[128 * 64];   // [d][key] 128 rows x 128B

    int lane = threadIdx.x & 63, w = threadIdx.x >> 6;
    int b = blockIdx.z, h = blockIdx.y;
    int q0 = blockIdx.x * 64 + w * 16;
    int qcol = lane & 15, quad = lane >> 4;

    // Q fragments (B-operand of 16x16x32): n = q = lane&15, k = d
    const unsigned short* qp = qh + (size_t)(b * SS + q0 + qcol) * DD + h * DHD;
    v8bf bq[4];
#pragma unroll
    for (int kk = 0; kk < 4; kk++)
        bq[kk] = __builtin_bit_cast(v8bf, *(const v8s*)(qp + kk * 32 + quad * 8));

    // --- staging addresses (element offsets within current tile) ---
    // K: wave w stages keys [w*16, w*16+16), 4 insts x 4 keys; lane covers
    // key = w*16 + j*4 + (lane>>4), global chunk (lane&15) ^ (key&15).
    int ko[4];
#pragma unroll
    for (int j = 0; j < 4; j++) {
        int key = w * 16 + j * 4 + (lane >> 4);
        ko[j] = key * DD + (((lane & 15) ^ (key & 15)) * 8);
    }
    // V: wave w stages d-rows [w*32, w*32+32), 4 insts x 8 rows; lane covers
    // d = w*32 + j*8 + (lane>>3), global chunk (lane&7) ^ (d&7).
    int vo0 = (w * 32 + (lane >> 3)) * SS + (((lane & 7) ^ (lane >> 3)) * 8);

    const unsigned short* kcur = kh + (size_t)b * SS * DD + h * DHD;
    const unsigned short* vcur = vt + (size_t)(b * HH + h) * DHD * SS;
    unsigned short* kl0 = &sK[(w * 16) * 128];
    unsigned short* vl0 = &sV[(w * 32) * 64];

    float m_i = -1e30f, l_i = 0.f;
    v4f acc[8];
#pragma unroll
    for (int c = 0; c < 8; c++) acc[c] = (v4f){0.f, 0.f, 0.f, 0.f};

    for (int kb = 0; kb < SS; kb += 64) {
        __syncthreads();   // previous tile's LDS reads complete
#pragma unroll
        for (int j = 0; j < 4; j++)
            __builtin_amdgcn_global_load_lds((const GLOBAL_AS void*)(kcur + ko[j]),
                                             (LDS_AS void*)(kl0 + j * 4 * 128), 16, 0, 0);
#pragma unroll
        for (int j = 0; j < 4; j++)
            __builtin_amdgcn_global_load_lds((const GLOBAL_AS void*)(vcur + vo0 + j * 8 * SS),
                                             (LDS_AS void*)(vl0 + j * 8 * 64), 16, 0, 0);
        kcur += (size_t)64 * DD;
        vcur += 64;
        __syncthreads();   // staging drained

        // S^T = K.Q^T : 16 MFMA 16x16x32, fragments from swizzled sK
        v4f s[4];
#pragma unroll
        for (int kf = 0; kf < 4; kf++) {
            s[kf] = (v4f){0.f, 0.f, 0.f, 0.f};
#pragma unroll
            for (int kk = 0; kk < 4; kk++) {
                v8bf ak = __builtin_bit_cast(v8bf,
                    *(const v8s*)&sK[(kf * 16 + qcol) * 128 + (((kk * 4 + quad) ^ qcol) * 8)]);
                s[kf] = __builtin_amdgcn_mfma_f32_16x16x32_bf16(ak, bq[kk], s[kf], 0, 0, 0);
            }
        }

        // online softmax over 64 keys (base-2; log2(e) folded into qh scale)
        float mx = -1e30f;
#pragma unroll
        for (int kf = 0; kf < 4; kf++)
#pragma unroll
            for (int r = 0; r < 4; r++) mx = fmaxf(mx, s[kf][r]);
        mx = fmaxf(mx, __shfl_xor(mx, 16));
        mx = fmaxf(mx, __shfl_xor(mx, 32));
        float m_new = fmaxf(m_i, mx);
        float rs = 0.f;
        v4s p[4];
#pragma unroll
        for (int kf = 0; kf < 4; kf++)
#pragma unroll
            for (int r = 0; r < 4; r++) {
                float pf = exp2f(s[kf][r] - m_new);
                rs += pf;
                p[kf][r] = (short)f2b(pf);
            }
        rs += __shfl_xor(rs, 16);
        rs += __shfl_xor(rs, 32);
        float alpha = exp2f(m_i - m_new);
        l_i = l_i * alpha + rs;
        m_i = m_new;
#pragma unroll
        for (int c = 0; c < 8; c++) {
            acc[c][0] *= alpha; acc[c][1] *= alpha;
            acc[c][2] *= alpha; acc[c][3] *= alpha;
        }

        // PV: 32 MFMA 16x16x16, V fragments from swizzled sV
#pragma unroll
        for (int c = 0; c < 8; c++) {
            int row = (c * 16 + qcol) * 64;
#pragma unroll
            for (int kf = 0; kf < 4; kf++) {
                v4s av = *(const v4s*)&sV[row + (((kf * 2 + (quad >> 1)) ^ (qcol & 7)) * 8)
                                              + (quad & 1) * 4];
                acc[c] = __builtin_amdgcn_mfma_f32_16x16x16bf16_1k(av, p[kf], acc[c], 0, 0, 0);
            }
        }
    }

    float rl = 1.0f / l_i;
    float* op = out + (size_t)(b * SS + q0 + qcol) * DD + h * DHD;
#pragma unroll
    for (int c = 0; c < 8; c++)
#pragma unroll
        for (int r = 0; r < 4; r++)
            op[c * 16 + quad * 4 + r] = acc[c][r] * rl;
}

// ---------------------------------------------------------------------------
// Launch. ws layout (needs 136 MB):
//   abuf @ 0 MB (32) | wbuf @ 32 (8) | qh @ 40 (32) | kh @ 72 (32) | vt @ 104 (32)
// ---------------------------------------------------------------------------
extern "C" void kernel_launch(void* const* d_in, const int* in_sizes, int n_in,
                              void* d_out, int out_size, void* d_ws, size_t ws_size,
                              hipStream_t stream) {
    const float* ins[3]  = {(const float*)d_in[0], (const float*)d_in[1], (const float*)d_in[2]};
    const float* wins[3] = {(const float*)d_in[3], (const float*)d_in[4], (const float*)d_in[5]};
    char* ws = (char*)d_ws;
    unsigned short* abuf = (unsigned short*)(ws);
    unsigned short* wbuf = (unsigned short*)(ws + (size_t)32 * 1024 * 1024);
    unsigned short* qhb  = (unsigned short*)(ws + (size_t)40 * 1024 * 1024);
    unsigned short* khb  = (unsigned short*)(ws + (size_t)72 * 1024 * 1024);
    unsigned short* vtb  = (unsigned short*)(ws + (size_t)104 * 1024 * 1024);
    float* out = (float*)d_out;

    unsigned short* outs[3] = {qhb, khb, vtb};
    const float qscale = 0.12753139626246937f;  // log2(e)/sqrt(128)
    float scales[3] = {qscale, 1.f, 1.f};
    int   vmodes[3] = {0, 0, 1};

    for (int i = 0; i < 3; i++) {
        cvt_f32_bf16<<<dim3(4096), dim3(256), 0, stream>>>(ins[i], abuf, (BB * SS * DD) / 4);
        wtrans_kernel<<<dim3(32, 32), dim3(256), 0, stream>>>(wins[i], wbuf);
        gemm_bt<<<dim3(16, 64), dim3(256), 0, stream>>>(abuf, wbuf, outs[i],
                                                        scales[i], vmodes[i],
                                                        BB * SS, DD, DD);
    }
    attn_kernel<<<dim3(SS / 64, HH, BB), dim3(256), 0, stream>>>(qhb, khb, vtb, out);
}